// Round 6
// baseline (137.938 us; speedup 1.0000x reference)
//
#include <hip/hip_runtime.h>
#include <math.h>

// WordLabelAttention on MI355X — Round 6: barrier-free attention main loop.
// N=4, H=8, D=64, E=512, KL=512, QROWS/n=2048.
//
//   kv_proj  : K -> Kp[nh][kl][d] bf16, V -> Vt[nh][d][kl] bf16 (MFMA).
//   attn     : fused q-proj + flash attention. Q fragments hoisted to VGPRs;
//              K/V fragments read DIRECTLY from global (L1/L2-hot, per-head
//              128 KB); mask as int4 broadcast loads -> acc-init bias;
//              p = exp2(s) (scale folded into Wq); P round-trips wave-private
//              LDS; ZERO __syncthreads in the kt loop. 3 blocks/CU.
//   out_gemm : AO @ Wo^T + bo (f32 out), register-prefetch pipeline.

typedef __bf16 bf16;
typedef __attribute__((ext_vector_type(8))) __bf16 bf16x8;
typedef __attribute__((ext_vector_type(4))) __bf16 bf16x4;
typedef __attribute__((ext_vector_type(4))) float f32x4;

#define LW 68  // LDS row stride (bf16) for fragment buffers
#define LS 72  // LDS row stride for SX (query-staging / P union)
#define QSCALE (0.044194173824159216f * 1.4426950408889634f)  // log2(e)/sqrt(512)
#define MASK_BIAS -64.0f

__device__ __forceinline__ bf16x8 cvt8(const float* p, float s) {
    float4 x0 = *(const float4*)p;
    float4 x1 = *(const float4*)(p + 4);
    return (bf16x8){(bf16)(x0.x * s), (bf16)(x0.y * s), (bf16)(x0.z * s), (bf16)(x0.w * s),
                    (bf16)(x1.x * s), (bf16)(x1.y * s), (bf16)(x1.z * s), (bf16)(x1.w * s)};
}

// ---------------------------------------------------------------- kv_proj
// grid 256 = 32 nh x 8 kl-tiles(64). block 256 (4 waves: w0-1 K, w2-3 V^T).
__global__ __launch_bounds__(256, 2) void kv_proj(const float* __restrict__ keys,
                                                  const float* __restrict__ values,
                                                  const float* __restrict__ Wk,
                                                  const float* __restrict__ Wv,
                                                  bf16* __restrict__ Kp,
                                                  bf16* __restrict__ Vt) {
    __shared__ bf16 Xk[64 * LW];
    __shared__ bf16 Xv[64 * LW];
    int t = threadIdx.x;
    int nh = blockIdx.x >> 3, kt = blockIdx.x & 7;
    int n = nh >> 3, h = nh & 7, kl0 = kt * 64;
    int w = t >> 6, quad = (t >> 4) & 3, c16 = t & 15;
#pragma unroll
    for (int i = 0; i < 4; ++i) {
        int f = t + i * 256, row = f >> 4, c4 = f & 15;
        float4 a = *(const float4*)(keys + ((long)n * 512 + kl0 + row) * 512 + h * 64 + c4 * 4);
        float4 b = *(const float4*)(values + ((long)n * 512 + kl0 + row) * 512 + h * 64 + c4 * 4);
        *(bf16x4*)&Xk[row * LW + c4 * 4] = (bf16x4){(bf16)a.x, (bf16)a.y, (bf16)a.z, (bf16)a.w};
        *(bf16x4*)&Xv[row * LW + c4 * 4] = (bf16x4){(bf16)b.x, (bf16)b.y, (bf16)b.z, (bf16)b.w};
    }
    __syncthreads();
    if (w < 2) {
        bf16x8 wf[8];
#pragma unroll
        for (int nb = 0; nb < 4; ++nb)
#pragma unroll
            for (int kc = 0; kc < 2; ++kc)
                wf[nb * 2 + kc] = cvt8(Wk + (16 * nb + c16) * 64 + 32 * kc + quad * 8, 1.0f);
        f32x4 acc[2][4];
#pragma unroll
        for (int mb = 0; mb < 2; ++mb)
#pragma unroll
            for (int nb = 0; nb < 4; ++nb) acc[mb][nb] = (f32x4){0.f, 0.f, 0.f, 0.f};
#pragma unroll
        for (int kc = 0; kc < 2; ++kc) {
            bf16x8 a0 = *(const bf16x8*)&Xk[(32 * w + c16) * LW + 32 * kc + quad * 8];
            bf16x8 a1 = *(const bf16x8*)&Xk[(32 * w + 16 + c16) * LW + 32 * kc + quad * 8];
#pragma unroll
            for (int nb = 0; nb < 4; ++nb) {
                acc[0][nb] = __builtin_amdgcn_mfma_f32_16x16x32_bf16(a0, wf[nb * 2 + kc], acc[0][nb], 0, 0, 0);
                acc[1][nb] = __builtin_amdgcn_mfma_f32_16x16x32_bf16(a1, wf[nb * 2 + kc], acc[1][nb], 0, 0, 0);
            }
        }
#pragma unroll
        for (int mb = 0; mb < 2; ++mb)
#pragma unroll
            for (int nb = 0; nb < 4; ++nb)
#pragma unroll
                for (int r = 0; r < 4; ++r)
                    Kp[((long)nh * 512 + kl0 + 32 * w + 16 * mb + quad * 4 + r) * 64 + 16 * nb + c16] =
                        (bf16)acc[mb][nb][r];
    } else {
        int w2 = w - 2;
        bf16x8 af[4];
#pragma unroll
        for (int mb = 0; mb < 2; ++mb)
#pragma unroll
            for (int kc = 0; kc < 2; ++kc)
                af[mb * 2 + kc] = cvt8(Wv + (32 * w2 + 16 * mb + c16) * 64 + 32 * kc + quad * 8, 1.0f);
        f32x4 acc[2][4];
#pragma unroll
        for (int mb = 0; mb < 2; ++mb)
#pragma unroll
            for (int nb = 0; nb < 4; ++nb) acc[mb][nb] = (f32x4){0.f, 0.f, 0.f, 0.f};
#pragma unroll
        for (int kc = 0; kc < 2; ++kc) {
#pragma unroll
            for (int nb = 0; nb < 4; ++nb) {
                bf16x8 b = *(const bf16x8*)&Xv[(16 * nb + c16) * LW + 32 * kc + quad * 8];
                acc[0][nb] = __builtin_amdgcn_mfma_f32_16x16x32_bf16(af[kc], b, acc[0][nb], 0, 0, 0);
                acc[1][nb] = __builtin_amdgcn_mfma_f32_16x16x32_bf16(af[2 + kc], b, acc[1][nb], 0, 0, 0);
            }
        }
#pragma unroll
        for (int mb = 0; mb < 2; ++mb)
#pragma unroll
            for (int nb = 0; nb < 4; ++nb)
#pragma unroll
                for (int r = 0; r < 4; ++r)
                    Vt[((long)nh * 64 + 32 * w2 + 16 * mb + quad * 4 + r) * 512 + kl0 + 16 * nb + c16] =
                        (bf16)acc[mb][nb][r];
    }
}

// ---------------------------------------------------------------- attn
// grid 512 = 16 q-tiles(128) x 32 nh, nh INNER (one head's 16 q-tile blocks
// land on one XCD -> K/V L2-hot). block 256, 32 q-rows/wave, 3 blocks/CU.
__global__ __launch_bounds__(256, 3) void attn(const float* __restrict__ query,
                                               const float* __restrict__ Wq,
                                               const bf16* __restrict__ Kp,
                                               const bf16* __restrict__ Vtg,
                                               const int* __restrict__ maskp,
                                               bf16* __restrict__ AO) {
    __shared__ bf16 SX[128 * LS];  // Xq staging, then P (wave-private rows)
    __shared__ bf16 Qt[128 * LW];
    int t = threadIdx.x;
    int nh = blockIdx.x & 31, qtile = blockIdx.x >> 5;
    int n = nh >> 3, h = nh & 7;
    int r0 = qtile * 128;
    int w = t >> 6, quad = (t >> 4) & 3, c16 = t & 15;
    const bf16* Kb = Kp + (long)nh * 512 * 64;
    const bf16* Vb = Vtg + (long)nh * 64 * 512;

    // Wq fragments in VGPRs (scale folded); dead after q-proj
    bf16x8 wf[8];
#pragma unroll
    for (int nb = 0; nb < 4; ++nb)
#pragma unroll
        for (int kc = 0; kc < 2; ++kc)
            wf[nb * 2 + kc] = cvt8(Wq + (16 * nb + c16) * 64 + 32 * kc + quad * 8, QSCALE);

    // stage raw query (f32 -> bf16)
#pragma unroll
    for (int i = 0; i < 8; ++i) {
        int f = t + i * 256, row = f >> 4, c4 = f & 15;
        float4 a = *(const float4*)(query + ((long)n * 2048 + r0 + row) * 512 + h * 64 + c4 * 4);
        *(bf16x4*)&SX[row * LS + c4 * 4] = (bf16x4){(bf16)a.x, (bf16)a.y, (bf16)a.z, (bf16)a.w};
    }
    __syncthreads();  // the ONLY barrier in this kernel
    // q-proj: Qt[row][d], wave-private rows 32w..32w+31
    {
        f32x4 qa[2][4];
#pragma unroll
        for (int mb = 0; mb < 2; ++mb)
#pragma unroll
            for (int nb = 0; nb < 4; ++nb) qa[mb][nb] = (f32x4){0.f, 0.f, 0.f, 0.f};
#pragma unroll
        for (int kc = 0; kc < 2; ++kc) {
            bf16x8 a0 = *(const bf16x8*)&SX[(32 * w + c16) * LS + 32 * kc + quad * 8];
            bf16x8 a1 = *(const bf16x8*)&SX[(32 * w + 16 + c16) * LS + 32 * kc + quad * 8];
#pragma unroll
            for (int nb = 0; nb < 4; ++nb) {
                qa[0][nb] = __builtin_amdgcn_mfma_f32_16x16x32_bf16(a0, wf[nb * 2 + kc], qa[0][nb], 0, 0, 0);
                qa[1][nb] = __builtin_amdgcn_mfma_f32_16x16x32_bf16(a1, wf[nb * 2 + kc], qa[1][nb], 0, 0, 0);
            }
        }
#pragma unroll
        for (int mb = 0; mb < 2; ++mb)
#pragma unroll
            for (int nb = 0; nb < 4; ++nb)
#pragma unroll
                for (int r = 0; r < 4; ++r)
                    Qt[(32 * w + 16 * mb + quad * 4 + r) * LW + 16 * nb + c16] = (bf16)qa[mb][nb][r];
    }
    // hoist Q fragments (wave-private rows; in-wave lgkmcnt orders write->read)
    bf16x8 qf[2][2];
#pragma unroll
    for (int nb = 0; nb < 2; ++nb)
#pragma unroll
        for (int kc = 0; kc < 2; ++kc)
            qf[nb][kc] = *(const bf16x8*)&Qt[(32 * w + 16 * nb + c16) * LW + 32 * kc + quad * 8];

    f32x4 oacc[4][2];
#pragma unroll
    for (int mb = 0; mb < 4; ++mb)
#pragma unroll
        for (int nb = 0; nb < 2; ++nb) oacc[mb][nb] = (f32x4){0.f, 0.f, 0.f, 0.f};
    float ps[2] = {0.f, 0.f};

    for (int kt = 0; kt < 8; ++kt) {
        // mask: int4 broadcast loads (keys 16mb+quad*4..+3), bias into acc-init
        int4 mk[4];
#pragma unroll
        for (int mb = 0; mb < 4; ++mb)
            mk[mb] = *(const int4*)(maskp + n * 512 + kt * 64 + 16 * mb + quad * 4);
        f32x4 sc[4][2];
#pragma unroll
        for (int mb = 0; mb < 4; ++mb) {
            f32x4 bias = {mk[mb].x ? 0.f : MASK_BIAS, mk[mb].y ? 0.f : MASK_BIAS,
                          mk[mb].z ? 0.f : MASK_BIAS, mk[mb].w ? 0.f : MASK_BIAS};
            sc[mb][0] = bias;
            sc[mb][1] = bias;
        }
        // S^T = K.Q^T : K fragments direct from global (L1/L2-hot)
#pragma unroll
        for (int kc = 0; kc < 2; ++kc) {
            bf16x8 ka[4];
#pragma unroll
            for (int mb = 0; mb < 4; ++mb)
                ka[mb] = *(const bf16x8*)(Kb + (long)(kt * 64 + 16 * mb + c16) * 64 + 32 * kc + quad * 8);
#pragma unroll
            for (int nb = 0; nb < 2; ++nb)
#pragma unroll
                for (int mb = 0; mb < 4; ++mb)
                    sc[mb][nb] = __builtin_amdgcn_mfma_f32_16x16x32_bf16(ka[mb], qf[nb][kc], sc[mb][nb], 0, 0, 0);
        }
        // p = exp2(s); l += p; packed b64 writes to wave-private P rows
#pragma unroll
        for (int mb = 0; mb < 4; ++mb)
#pragma unroll
            for (int nb = 0; nb < 2; ++nb) {
                float p0 = exp2f(sc[mb][nb][0]);
                float p1 = exp2f(sc[mb][nb][1]);
                float p2 = exp2f(sc[mb][nb][2]);
                float p3 = exp2f(sc[mb][nb][3]);
                ps[nb] += (p0 + p1) + (p2 + p3);
                *(bf16x4*)&SX[(32 * w + 16 * nb + c16) * LS + 16 * mb + quad * 4] =
                    (bf16x4){(bf16)p0, (bf16)p1, (bf16)p2, (bf16)p3};
            }
        // O^T += V.P^T : V fragments direct from global, P from wave-private LDS
#pragma unroll
        for (int kc = 0; kc < 2; ++kc) {
            bf16x8 va[4];
#pragma unroll
            for (int mb = 0; mb < 4; ++mb)
                va[mb] = *(const bf16x8*)(Vb + (long)(16 * mb + c16) * 512 + kt * 64 + 32 * kc + quad * 8);
#pragma unroll
            for (int nb = 0; nb < 2; ++nb) {
                bf16x8 pb = *(const bf16x8*)&SX[(32 * w + 16 * nb + c16) * LS + 32 * kc + quad * 8];
#pragma unroll
                for (int mb = 0; mb < 4; ++mb)
                    oacc[mb][nb] = __builtin_amdgcn_mfma_f32_16x16x32_bf16(va[mb], pb, oacc[mb][nb], 0, 0, 0);
            }
        }
    }
#pragma unroll
    for (int nb = 0; nb < 2; ++nb) {
        ps[nb] += __shfl_xor(ps[nb], 16);
        ps[nb] += __shfl_xor(ps[nb], 32);
    }
    float il[2] = {1.0f / ps[0], 1.0f / ps[1]};
#pragma unroll
    for (int mb = 0; mb < 4; ++mb)
#pragma unroll
        for (int nb = 0; nb < 2; ++nb) {
            int row_g = r0 + 32 * w + 16 * nb + c16;
            *(bf16x4*)(AO + ((long)n * 2048 + row_g) * 512 + h * 64 + 16 * mb + quad * 4) =
                (bf16x4){(bf16)(oacc[mb][nb][0] * il[nb]), (bf16)(oacc[mb][nb][1] * il[nb]),
                         (bf16)(oacc[mb][nb][2] * il[nb]), (bf16)(oacc[mb][nb][3] * il[nb])};
        }
}

// ---------------------------------------------------------------- out_gemm
// C[8192][512] = AO @ Wo^T + bo. grid 512: br INNER (XCD locality), 64 row x
// 8 col tiles. block 256, BK=64, register-prefetch of next k-chunk.
__global__ __launch_bounds__(256, 2) void out_gemm(const bf16* __restrict__ A,
                                                   const float* __restrict__ Wo,
                                                   const float* __restrict__ bo,
                                                   float* __restrict__ C) {
    __shared__ bf16 At[128 * LW];
    __shared__ bf16 Bt[64 * LW];
    int t = threadIdx.x;
    int br = blockIdx.x & 63, bc = blockIdx.x >> 6;
    int r0 = br * 128, c0 = bc * 64;
    int w = t >> 6, quad = (t >> 4) & 3, c16 = t & 15;
    int arow[4], acol[4], wrow[4], wcol[4];
#pragma unroll
    for (int i = 0; i < 4; ++i) {
        int f = t + i * 256;
        arow[i] = f >> 3;
        acol[i] = f & 7;
        wrow[i] = f >> 4;
        wcol[i] = f & 15;
    }
    bf16x8 pa[4];
    float4 pw[4];
#pragma unroll
    for (int i = 0; i < 4; ++i) {
        pa[i] = *(const bf16x8*)(A + (long)(r0 + arow[i]) * 512 + acol[i] * 8);
        pw[i] = *(const float4*)(Wo + (long)(c0 + wrow[i]) * 512 + wcol[i] * 4);
    }
    f32x4 acc[2][4];
#pragma unroll
    for (int mb = 0; mb < 2; ++mb)
#pragma unroll
        for (int nb = 0; nb < 4; ++nb) acc[mb][nb] = (f32x4){0.f, 0.f, 0.f, 0.f};
    for (int k0 = 0; k0 < 512; k0 += 64) {
        if (k0) __syncthreads();
#pragma unroll
        for (int i = 0; i < 4; ++i) {
            *(bf16x8*)&At[arow[i] * LW + acol[i] * 8] = pa[i];
            *(bf16x4*)&Bt[wrow[i] * LW + wcol[i] * 4] =
                (bf16x4){(bf16)pw[i].x, (bf16)pw[i].y, (bf16)pw[i].z, (bf16)pw[i].w};
        }
        __syncthreads();
        if (k0 < 448) {
#pragma unroll
            for (int i = 0; i < 4; ++i) {
                pa[i] = *(const bf16x8*)(A + (long)(r0 + arow[i]) * 512 + k0 + 64 + acol[i] * 8);
                pw[i] = *(const float4*)(Wo + (long)(c0 + wrow[i]) * 512 + k0 + 64 + wcol[i] * 4);
            }
        }
#pragma unroll
        for (int kc = 0; kc < 2; ++kc) {
            bf16x8 a0 = *(const bf16x8*)&At[(32 * w + c16) * LW + 32 * kc + quad * 8];
            bf16x8 a1 = *(const bf16x8*)&At[(32 * w + 16 + c16) * LW + 32 * kc + quad * 8];
#pragma unroll
            for (int nb = 0; nb < 4; ++nb) {
                bf16x8 b = *(const bf16x8*)&Bt[(16 * nb + c16) * LW + 32 * kc + quad * 8];
                acc[0][nb] = __builtin_amdgcn_mfma_f32_16x16x32_bf16(a0, b, acc[0][nb], 0, 0, 0);
                acc[1][nb] = __builtin_amdgcn_mfma_f32_16x16x32_bf16(a1, b, acc[1][nb], 0, 0, 0);
            }
        }
    }
#pragma unroll
    for (int mb = 0; mb < 2; ++mb)
#pragma unroll
        for (int nb = 0; nb < 4; ++nb) {
            float bias = bo[c0 + 16 * nb + c16];
#pragma unroll
            for (int r = 0; r < 4; ++r)
                C[(long)(r0 + 32 * w + 16 * mb + quad * 4 + r) * 512 + c0 + 16 * nb + c16] =
                    acc[mb][nb][r] + bias;
        }
}

extern "C" void kernel_launch(void* const* d_in, const int* in_sizes, int n_in,
                              void* d_out, int out_size, void* d_ws, size_t ws_size,
                              hipStream_t stream) {
    const float* values = (const float*)d_in[0];
    const float* keys   = (const float*)d_in[1];
    const float* query  = (const float*)d_in[2];
    const int*   maskp  = (const int*)d_in[3];
    const float* Wv     = (const float*)d_in[4];
    const float* Wk     = (const float*)d_in[5];
    const float* Wq     = (const float*)d_in[6];
    const float* Wo     = (const float*)d_in[7];
    const float* bo     = (const float*)d_in[8];
    float* out = (float*)d_out;

    bf16* ws = (bf16*)d_ws;
    bf16* Kp = ws;              // 1,048,576 bf16
    bf16* Vt = Kp + 1048576;    // 1,048,576
    bf16* AO = Vt + 1048576;    // 4,194,304

    kv_proj<<<dim3(256), dim3(256), 0, stream>>>(keys, values, Wk, Wv, Kp, Vt);
    attn<<<dim3(512), dim3(256), 0, stream>>>(query, Wq, Kp, Vt, maskp, AO);
    out_gemm<<<dim3(512), dim3(256), 0, stream>>>(AO, Wo, bo, out);
}

// Round 7
// 128.976 us; speedup vs baseline: 1.0695x; 1.0695x over previous
//
#include <hip/hip_runtime.h>
#include <math.h>

// WordLabelAttention on MI355X — Round 7: attn occupancy 2->4 blocks/CU.
// N=4, H=8, D=64, E=512, KL=512, QROWS/n=2048.
//
//   kv_proj  : K -> Kp[nh][kl][d] bf16, V -> Vt[nh][d][kl] bf16 (MFMA).
//   attn     : 64-row q-tiles, grid 1024 (4 blocks/CU), block 256 (4 waves,
//              16 q-rows/wave). LDS-staged K/V tiles (shared by 4 waves) with
//              register prefetch of the next tile; Q fragments hoisted to
//              VGPRs; SX buffer reused Xq -> Qt -> P (wave-private rows);
//              S^T = K.Q^T with mask bias as acc-init; p = exp2(s) (scale
//              folded into Wq); O^T = V.P^T; deferred normalization.
//              LDS 26.9 KB, __launch_bounds__(256,4) -> 16 waves/CU.
//   out_gemm : AO @ Wo^T + bo (f32 out), register-prefetch pipeline.

typedef __bf16 bf16;
typedef __attribute__((ext_vector_type(8))) __bf16 bf16x8;
typedef __attribute__((ext_vector_type(4))) __bf16 bf16x4;
typedef __attribute__((ext_vector_type(4))) float f32x4;

#define LW 68  // LDS row stride (bf16) for Kt/Vs/At/Bt
#define LS 72  // LDS row stride for SX
#define QSCALE (0.044194173824159216f * 1.4426950408889634f)  // log2(e)/sqrt(512)
#define MASK_BIAS -64.0f

__device__ __forceinline__ bf16x8 cvt8(const float* p, float s) {
    float4 x0 = *(const float4*)p;
    float4 x1 = *(const float4*)(p + 4);
    return (bf16x8){(bf16)(x0.x * s), (bf16)(x0.y * s), (bf16)(x0.z * s), (bf16)(x0.w * s),
                    (bf16)(x1.x * s), (bf16)(x1.y * s), (bf16)(x1.z * s), (bf16)(x1.w * s)};
}

// ---------------------------------------------------------------- kv_proj
// grid 256 = 32 nh x 8 kl-tiles(64). block 256 (4 waves: w0-1 K, w2-3 V^T).
__global__ __launch_bounds__(256, 2) void kv_proj(const float* __restrict__ keys,
                                                  const float* __restrict__ values,
                                                  const float* __restrict__ Wk,
                                                  const float* __restrict__ Wv,
                                                  bf16* __restrict__ Kp,
                                                  bf16* __restrict__ Vt) {
    __shared__ bf16 Xk[64 * LW];
    __shared__ bf16 Xv[64 * LW];
    int t = threadIdx.x;
    int nh = blockIdx.x >> 3, kt = blockIdx.x & 7;
    int n = nh >> 3, h = nh & 7, kl0 = kt * 64;
    int w = t >> 6, quad = (t >> 4) & 3, c16 = t & 15;
#pragma unroll
    for (int i = 0; i < 4; ++i) {
        int f = t + i * 256, row = f >> 4, c4 = f & 15;
        float4 a = *(const float4*)(keys + ((long)n * 512 + kl0 + row) * 512 + h * 64 + c4 * 4);
        float4 b = *(const float4*)(values + ((long)n * 512 + kl0 + row) * 512 + h * 64 + c4 * 4);
        *(bf16x4*)&Xk[row * LW + c4 * 4] = (bf16x4){(bf16)a.x, (bf16)a.y, (bf16)a.z, (bf16)a.w};
        *(bf16x4*)&Xv[row * LW + c4 * 4] = (bf16x4){(bf16)b.x, (bf16)b.y, (bf16)b.z, (bf16)b.w};
    }
    __syncthreads();
    if (w < 2) {
        bf16x8 wf[8];
#pragma unroll
        for (int nb = 0; nb < 4; ++nb)
#pragma unroll
            for (int kc = 0; kc < 2; ++kc)
                wf[nb * 2 + kc] = cvt8(Wk + (16 * nb + c16) * 64 + 32 * kc + quad * 8, 1.0f);
        f32x4 acc[2][4];
#pragma unroll
        for (int mb = 0; mb < 2; ++mb)
#pragma unroll
            for (int nb = 0; nb < 4; ++nb) acc[mb][nb] = (f32x4){0.f, 0.f, 0.f, 0.f};
#pragma unroll
        for (int kc = 0; kc < 2; ++kc) {
            bf16x8 a0 = *(const bf16x8*)&Xk[(32 * w + c16) * LW + 32 * kc + quad * 8];
            bf16x8 a1 = *(const bf16x8*)&Xk[(32 * w + 16 + c16) * LW + 32 * kc + quad * 8];
#pragma unroll
            for (int nb = 0; nb < 4; ++nb) {
                acc[0][nb] = __builtin_amdgcn_mfma_f32_16x16x32_bf16(a0, wf[nb * 2 + kc], acc[0][nb], 0, 0, 0);
                acc[1][nb] = __builtin_amdgcn_mfma_f32_16x16x32_bf16(a1, wf[nb * 2 + kc], acc[1][nb], 0, 0, 0);
            }
        }
#pragma unroll
        for (int mb = 0; mb < 2; ++mb)
#pragma unroll
            for (int nb = 0; nb < 4; ++nb)
#pragma unroll
                for (int r = 0; r < 4; ++r)
                    Kp[((long)nh * 512 + kl0 + 32 * w + 16 * mb + quad * 4 + r) * 64 + 16 * nb + c16] =
                        (bf16)acc[mb][nb][r];
    } else {
        int w2 = w - 2;
        bf16x8 af[4];
#pragma unroll
        for (int mb = 0; mb < 2; ++mb)
#pragma unroll
            for (int kc = 0; kc < 2; ++kc)
                af[mb * 2 + kc] = cvt8(Wv + (32 * w2 + 16 * mb + c16) * 64 + 32 * kc + quad * 8, 1.0f);
        f32x4 acc[2][4];
#pragma unroll
        for (int mb = 0; mb < 2; ++mb)
#pragma unroll
            for (int nb = 0; nb < 4; ++nb) acc[mb][nb] = (f32x4){0.f, 0.f, 0.f, 0.f};
#pragma unroll
        for (int kc = 0; kc < 2; ++kc) {
#pragma unroll
            for (int nb = 0; nb < 4; ++nb) {
                bf16x8 b = *(const bf16x8*)&Xv[(16 * nb + c16) * LW + 32 * kc + quad * 8];
                acc[0][nb] = __builtin_amdgcn_mfma_f32_16x16x32_bf16(af[kc], b, acc[0][nb], 0, 0, 0);
                acc[1][nb] = __builtin_amdgcn_mfma_f32_16x16x32_bf16(af[2 + kc], b, acc[1][nb], 0, 0, 0);
            }
        }
#pragma unroll
        for (int mb = 0; mb < 2; ++mb)
#pragma unroll
            for (int nb = 0; nb < 4; ++nb)
#pragma unroll
                for (int r = 0; r < 4; ++r)
                    Vt[((long)nh * 64 + 32 * w2 + 16 * mb + quad * 4 + r) * 512 + kl0 + 16 * nb + c16] =
                        (bf16)acc[mb][nb][r];
    }
}

// ---------------------------------------------------------------- attn
// grid 1024 = 32 q-tiles(64 rows) x 32 nh, nh INNER (XCD K/V locality).
// block 256 (4 waves, 16 q-rows/wave). 4 blocks/CU.
__global__ __launch_bounds__(256, 4) void attn(const float* __restrict__ query,
                                               const float* __restrict__ Wq,
                                               const bf16* __restrict__ Kp,
                                               const bf16* __restrict__ Vtg,
                                               const int* __restrict__ maskp,
                                               bf16* __restrict__ AO) {
    __shared__ bf16 SX[64 * LS];   // Xq -> Qt -> P (all rows wave-private)
    __shared__ bf16 Kt[64 * LW];
    __shared__ bf16 Vs[64 * LW];
    __shared__ float Mb[64];
    int t = threadIdx.x;
    int nh = blockIdx.x & 31, qtile = blockIdx.x >> 5;
    int n = nh >> 3, h = nh & 7;
    int r0 = qtile * 64;
    int w = t >> 6, quad = (t >> 4) & 3, c16 = t & 15;
    const bf16* Kb = Kp + (long)nh * 512 * 64;
    const bf16* Vb = Vtg + (long)nh * 64 * 512;

    // tile-0 K/V/mask prefetch (drains during q-proj)
    int prow0 = t >> 3, pcol0 = t & 7;
    int prow1 = (t + 256) >> 3, pcol1 = t & 7;
    bf16x8 pk0 = *(const bf16x8*)(Kb + (long)prow0 * 64 + pcol0 * 8);
    bf16x8 pk1 = *(const bf16x8*)(Kb + (long)prow1 * 64 + pcol1 * 8);
    bf16x8 pv0 = *(const bf16x8*)(Vb + (long)prow0 * 512 + pcol0 * 8);
    bf16x8 pv1 = *(const bf16x8*)(Vb + (long)prow1 * 512 + pcol1 * 8);
    float mnext = 0.f;
    if (t < 64) mnext = maskp[n * 512 + t] ? 0.f : MASK_BIAS;

    // Wq fragments (scale folded); dead after q-proj
    bf16x8 wf[8];
#pragma unroll
    for (int nb = 0; nb < 4; ++nb)
#pragma unroll
        for (int kc = 0; kc < 2; ++kc)
            wf[nb * 2 + kc] = cvt8(Wq + (16 * nb + c16) * 64 + 32 * kc + quad * 8, QSCALE);

    // stage raw query rows 16w..16w+15 (WAVE-PRIVATE staging: no barrier)
    {
        int l = t & 63;
        int rloc = 16 * w + (l >> 2);
        const float* qrow = query + ((long)n * 2048 + r0 + rloc) * 512 + h * 64;
#pragma unroll
        for (int j = 0; j < 4; ++j) {
            int c = (l & 3) + 4 * j;
            float4 a = *(const float4*)(qrow + c * 4);
            *(bf16x4*)&SX[rloc * LS + c * 4] = (bf16x4){(bf16)a.x, (bf16)a.y, (bf16)a.z, (bf16)a.w};
        }
    }
    // q-proj: C[row][d], 16 rows (this wave's), A-frags from wave-private SX rows
    f32x4 qa[4];
#pragma unroll
    for (int nb = 0; nb < 4; ++nb) qa[nb] = (f32x4){0.f, 0.f, 0.f, 0.f};
#pragma unroll
    for (int kc = 0; kc < 2; ++kc) {
        bf16x8 a = *(const bf16x8*)&SX[(16 * w + c16) * LS + 32 * kc + quad * 8];
#pragma unroll
        for (int nb = 0; nb < 4; ++nb)
            qa[nb] = __builtin_amdgcn_mfma_f32_16x16x32_bf16(a, wf[nb * 2 + kc], qa[nb], 0, 0, 0);
    }
    // write Qt (C-layout) into SX, then hoist A-layout Q fragments to VGPRs
#pragma unroll
    for (int nb = 0; nb < 4; ++nb)
#pragma unroll
        for (int r = 0; r < 4; ++r)
            SX[(16 * w + quad * 4 + r) * LS + 16 * nb + c16] = (bf16)qa[nb][r];
    bf16x8 qf[2];
#pragma unroll
    for (int kc = 0; kc < 2; ++kc)
        qf[kc] = *(const bf16x8*)&SX[(16 * w + c16) * LS + 32 * kc + quad * 8];

    f32x4 oacc[4];
#pragma unroll
    for (int mb = 0; mb < 4; ++mb) oacc[mb] = (f32x4){0.f, 0.f, 0.f, 0.f};
    float ps = 0.f;

    for (int kt = 0; kt < 8; ++kt) {
        if (kt) __syncthreads();  // all waves done reading prev Kt/Vs
        *(bf16x8*)&Kt[prow0 * LW + pcol0 * 8] = pk0;
        *(bf16x8*)&Kt[prow1 * LW + pcol1 * 8] = pk1;
        *(bf16x8*)&Vs[prow0 * LW + pcol0 * 8] = pv0;
        *(bf16x8*)&Vs[prow1 * LW + pcol1 * 8] = pv1;
        if (t < 64) Mb[t] = mnext;
        __syncthreads();
        if (kt < 7) {  // register prefetch of next tile, drains under compute
            const bf16* Kn = Kb + (long)(kt + 1) * 64 * 64;
            const bf16* Vn = Vb + (kt + 1) * 64;
            pk0 = *(const bf16x8*)(Kn + (long)prow0 * 64 + pcol0 * 8);
            pk1 = *(const bf16x8*)(Kn + (long)prow1 * 64 + pcol1 * 8);
            pv0 = *(const bf16x8*)(Vn + (long)prow0 * 512 + pcol0 * 8);
            pv1 = *(const bf16x8*)(Vn + (long)prow1 * 512 + pcol1 * 8);
            if (t < 64) mnext = maskp[n * 512 + (kt + 1) * 64 + t] ? 0.f : MASK_BIAS;
        }
        // S^T = K.Q^T + mask bias (acc-init). m=key (4 blocks), n = 16 q-rows
        f32x4 sc[4];
#pragma unroll
        for (int mb = 0; mb < 4; ++mb) sc[mb] = *(const f32x4*)&Mb[16 * mb + quad * 4];
#pragma unroll
        for (int kc = 0; kc < 2; ++kc) {
#pragma unroll
            for (int mb = 0; mb < 4; ++mb) {
                bf16x8 ka = *(const bf16x8*)&Kt[(16 * mb + c16) * LW + 32 * kc + quad * 8];
                sc[mb] = __builtin_amdgcn_mfma_f32_16x16x32_bf16(ka, qf[kc], sc[mb], 0, 0, 0);
            }
        }
        // p = exp2(s); l += p; P into wave-private SX rows [qrow][key]
#pragma unroll
        for (int mb = 0; mb < 4; ++mb) {
            float p0 = exp2f(sc[mb][0]);
            float p1 = exp2f(sc[mb][1]);
            float p2 = exp2f(sc[mb][2]);
            float p3 = exp2f(sc[mb][3]);
            ps += (p0 + p1) + (p2 + p3);
            *(bf16x4*)&SX[(16 * w + c16) * LS + 16 * mb + quad * 4] =
                (bf16x4){(bf16)p0, (bf16)p1, (bf16)p2, (bf16)p3};
        }
        // NOTE: ps accumulated per-thread covers q-row 16w+c16 across quads' keys
        // O^T += V.P^T (A=Vs[d][key] shared, B=P wave-private)
#pragma unroll
        for (int kc = 0; kc < 2; ++kc) {
            bf16x8 pb = *(const bf16x8*)&SX[(16 * w + c16) * LS + 32 * kc + quad * 8];
#pragma unroll
            for (int mb = 0; mb < 4; ++mb) {
                bf16x8 va = *(const bf16x8*)&Vs[(16 * mb + c16) * LW + 32 * kc + quad * 8];
                oacc[mb] = __builtin_amdgcn_mfma_f32_16x16x32_bf16(va, pb, oacc[mb], 0, 0, 0);
            }
        }
    }
    // l for q-row 16w+c16: reduce across quads (same c16)
    ps += __shfl_xor(ps, 16);
    ps += __shfl_xor(ps, 32);
    float il = 1.0f / ps;
    int row_g = r0 + 16 * w + c16;
#pragma unroll
    for (int mb = 0; mb < 4; ++mb)
        *(bf16x4*)(AO + ((long)n * 2048 + row_g) * 512 + h * 64 + 16 * mb + quad * 4) =
            (bf16x4){(bf16)(oacc[mb][0] * il), (bf16)(oacc[mb][1] * il),
                     (bf16)(oacc[mb][2] * il), (bf16)(oacc[mb][3] * il)};
}

// ---------------------------------------------------------------- out_gemm
// C[8192][512] = AO @ Wo^T + bo. grid 512: br INNER (XCD locality), 64 row x
// 8 col tiles. block 256, BK=64, register-prefetch of next k-chunk.
__global__ __launch_bounds__(256, 2) void out_gemm(const bf16* __restrict__ A,
                                                   const float* __restrict__ Wo,
                                                   const float* __restrict__ bo,
                                                   float* __restrict__ C) {
    __shared__ bf16 At[128 * LW];
    __shared__ bf16 Bt[64 * LW];
    int t = threadIdx.x;
    int br = blockIdx.x & 63, bc = blockIdx.x >> 6;
    int r0 = br * 128, c0 = bc * 64;
    int w = t >> 6, quad = (t >> 4) & 3, c16 = t & 15;
    int arow[4], acol[4], wrow[4], wcol[4];
#pragma unroll
    for (int i = 0; i < 4; ++i) {
        int f = t + i * 256;
        arow[i] = f >> 3;
        acol[i] = f & 7;
        wrow[i] = f >> 4;
        wcol[i] = f & 15;
    }
    bf16x8 pa[4];
    float4 pw[4];
#pragma unroll
    for (int i = 0; i < 4; ++i) {
        pa[i] = *(const bf16x8*)(A + (long)(r0 + arow[i]) * 512 + acol[i] * 8);
        pw[i] = *(const float4*)(Wo + (long)(c0 + wrow[i]) * 512 + wcol[i] * 4);
    }
    f32x4 acc[2][4];
#pragma unroll
    for (int mb = 0; mb < 2; ++mb)
#pragma unroll
        for (int nb = 0; nb < 4; ++nb) acc[mb][nb] = (f32x4){0.f, 0.f, 0.f, 0.f};
    for (int k0 = 0; k0 < 512; k0 += 64) {
        if (k0) __syncthreads();
#pragma unroll
        for (int i = 0; i < 4; ++i) {
            *(bf16x8*)&At[arow[i] * LW + acol[i] * 8] = pa[i];
            *(bf16x4*)&Bt[wrow[i] * LW + wcol[i] * 4] =
                (bf16x4){(bf16)pw[i].x, (bf16)pw[i].y, (bf16)pw[i].z, (bf16)pw[i].w};
        }
        __syncthreads();
        if (k0 < 448) {
#pragma unroll
            for (int i = 0; i < 4; ++i) {
                pa[i] = *(const bf16x8*)(A + (long)(r0 + arow[i]) * 512 + k0 + 64 + acol[i] * 8);
                pw[i] = *(const float4*)(Wo + (long)(c0 + wrow[i]) * 512 + k0 + 64 + wcol[i] * 4);
            }
        }
#pragma unroll
        for (int kc = 0; kc < 2; ++kc) {
            bf16x8 a0 = *(const bf16x8*)&At[(32 * w + c16) * LW + 32 * kc + quad * 8];
            bf16x8 a1 = *(const bf16x8*)&At[(32 * w + 16 + c16) * LW + 32 * kc + quad * 8];
#pragma unroll
            for (int nb = 0; nb < 4; ++nb) {
                bf16x8 b = *(const bf16x8*)&Bt[(16 * nb + c16) * LW + 32 * kc + quad * 8];
                acc[0][nb] = __builtin_amdgcn_mfma_f32_16x16x32_bf16(a0, b, acc[0][nb], 0, 0, 0);
                acc[1][nb] = __builtin_amdgcn_mfma_f32_16x16x32_bf16(a1, b, acc[1][nb], 0, 0, 0);
            }
        }
    }
#pragma unroll
    for (int mb = 0; mb < 2; ++mb)
#pragma unroll
        for (int nb = 0; nb < 4; ++nb) {
            float bias = bo[c0 + 16 * nb + c16];
#pragma unroll
            for (int r = 0; r < 4; ++r)
                C[(long)(r0 + 32 * w + 16 * mb + quad * 4 + r) * 512 + c0 + 16 * nb + c16] =
                    acc[mb][nb][r] + bias;
        }
}

extern "C" void kernel_launch(void* const* d_in, const int* in_sizes, int n_in,
                              void* d_out, int out_size, void* d_ws, size_t ws_size,
                              hipStream_t stream) {
    const float* values = (const float*)d_in[0];
    const float* keys   = (const float*)d_in[1];
    const float* query  = (const float*)d_in[2];
    const int*   maskp  = (const int*)d_in[3];
    const float* Wv     = (const float*)d_in[4];
    const float* Wk     = (const float*)d_in[5];
    const float* Wq     = (const float*)d_in[6];
    const float* Wo     = (const float*)d_in[7];
    const float* bo     = (const float*)d_in[8];
    float* out = (float*)d_out;

    bf16* ws = (bf16*)d_ws;
    bf16* Kp = ws;              // 1,048,576 bf16
    bf16* Vt = Kp + 1048576;    // 1,048,576
    bf16* AO = Vt + 1048576;    // 4,194,304

    kv_proj<<<dim3(256), dim3(256), 0, stream>>>(keys, values, Wk, Wv, Kp, Vt);
    attn<<<dim3(1024), dim3(256), 0, stream>>>(query, Wq, Kp, Vt, maskp, AO);
    out_gemm<<<dim3(512), dim3(256), 0, stream>>>(AO, Wo, bo, out);
}